// Round 1
// baseline (168.834 us; speedup 1.0000x reference)
//
#include <hip/hip_runtime.h>

typedef __bf16 bf16;
typedef __bf16 bf16x4 __attribute__((ext_vector_type(4)));
typedef __bf16 bf16x8 __attribute__((ext_vector_type(8)));
typedef float f32x4 __attribute__((ext_vector_type(4)));

#define MFMA16(a, b, c) __builtin_amdgcn_mfma_f32_16x16x32_bf16((a), (b), (c), 0, 0, 0)

// Problem sizes
// B=256, T=320, C=1024, H=64;  M = B*T = 81920
// ws layout (bf16 elems):
//   Wt : [3][64][1024]            (196608)
//   Qw : [81920][64]              (5242880)
//   Kw : [81920][64]              (5242880)
//   Vt : [256][64][320]           (5242880)

// ---------------- Kernel 0: W -> Wt (bf16, [mat][h][k]) ----------------
__global__ __launch_bounds__(256) void wtrans_kernel(
    const float* __restrict__ Wk, const float* __restrict__ Wq,
    const float* __restrict__ Wv, bf16* __restrict__ Wt) {
  __shared__ bf16 tile[64][65];
  const int mat = blockIdx.x >> 4;
  const int kt = (blockIdx.x & 15) << 6;
  const float* __restrict__ W = (mat == 0) ? Wk : ((mat == 1) ? Wq : Wv);
  const int tid = threadIdx.x;
#pragma unroll
  for (int j = 0; j < 16; ++j) {
    const int i = tid + 256 * j;
    const int k = i >> 6, h = i & 63;
    tile[h][k] = (bf16)W[(kt + k) * 64 + h];  // coalesced read
  }
  __syncthreads();
#pragma unroll
  for (int j = 0; j < 16; ++j) {
    const int i = tid + 256 * j;
    const int h = i >> 6, k = i & 63;
    Wt[mat * 65536 + h * 1024 + kt + k] = tile[h][k];  // coalesced write
  }
}

// ---------------- Kernel 1: fused QKV projection (bf16 MFMA) ----------------
// grid 1280 blocks, 256 thr (4 waves). Block: 64 rows x 192 cols. Wave: 64x48.
__global__ __launch_bounds__(256) void qkv_kernel(
    const float* __restrict__ x, const bf16* __restrict__ Wt,
    bf16* __restrict__ Qw, bf16* __restrict__ Kw, bf16* __restrict__ Vt) {
  __shared__ bf16 xs[64][72];  // +8 pad: 2-way banks on b128 reads (free)
  const int tid = threadIdx.x;
  const int w = tid >> 6, l = tid & 63;
  const int lr = l & 15, lg = l >> 4;
  const int m0 = blockIdx.x * 64;

  f32x4 acc[4][3];
#pragma unroll
  for (int mf = 0; mf < 4; ++mf)
#pragma unroll
    for (int nf = 0; nf < 3; ++nf) acc[mf][nf] = (f32x4)0.0f;

  for (int kt = 0; kt < 1024; kt += 64) {
    // stage x tile [64][64] fp32 -> bf16 LDS
#pragma unroll
    for (int j = 0; j < 4; ++j) {
      const int u = tid + 256 * j;
      const int row = u >> 4, f4 = u & 15;
      const float4 g = *(const float4*)(x + (size_t)(m0 + row) * 1024 + kt + f4 * 4);
      bf16x4 h4;
      h4[0] = (bf16)g.x; h4[1] = (bf16)g.y; h4[2] = (bf16)g.z; h4[3] = (bf16)g.w;
      *(bf16x4*)(&xs[row][f4 * 4]) = h4;
    }
    __syncthreads();

    // B fragments straight from L2-resident Wt (k-contiguous)
    bf16x8 bfr[3][2];
#pragma unroll
    for (int nf = 0; nf < 3; ++nf) {
      const int colg = w * 48 + nf * 16 + lr;  // 16-col frag never straddles a matrix
      const int mat = colg >> 6, h = colg & 63;
      const bf16* p = Wt + mat * 65536 + h * 1024 + kt + lg * 8;
      bfr[nf][0] = *(const bf16x8*)p;
      bfr[nf][1] = *(const bf16x8*)(p + 32);
    }
#pragma unroll
    for (int mf = 0; mf < 4; ++mf) {
      const bf16x8 a0 = *(const bf16x8*)(&xs[mf * 16 + lr][lg * 8]);
      const bf16x8 a1 = *(const bf16x8*)(&xs[mf * 16 + lr][32 + lg * 8]);
#pragma unroll
      for (int nf = 0; nf < 3; ++nf) {
        acc[mf][nf] = MFMA16(a0, bfr[nf][0], acc[mf][nf]);
        acc[mf][nf] = MFMA16(a1, bfr[nf][1], acc[mf][nf]);
      }
    }
    __syncthreads();
  }

  // epilogue: C/D layout col=lane&15, row=(lane>>4)*4+r
#pragma unroll
  for (int mf = 0; mf < 4; ++mf) {
#pragma unroll
    for (int nf = 0; nf < 3; ++nf) {
      const int colg = w * 48 + nf * 16 + lr;
      const int mat = colg >> 6, h = colg & 63;
      const int mb = m0 + mf * 16 + lg * 4;  // 64 | 320 so block stays in one batch
      if (mat == 2) {  // value -> transposed [b][h][t], 4 consecutive t = 8B store
        const int b = mb / 320, t = mb % 320;
        bf16x4 o;
#pragma unroll
        for (int r = 0; r < 4; ++r) o[r] = (bf16)acc[mf][nf][r];
        *(bf16x4*)(Vt + ((size_t)b * 64 + h) * 320 + t) = o;
      } else {
        bf16* __restrict__ dst = (mat == 0) ? Kw : Qw;
#pragma unroll
        for (int r = 0; r < 4; ++r) dst[(size_t)(mb + r) * 64 + h] = (bf16)acc[mf][nf][r];
      }
    }
  }
}

// ---------------- Kernel 2: causal attention, one (b, qtile) per block ----------------
template <int QT>
__device__ __forceinline__ void attn_impl(
    int b, const bf16* __restrict__ Qw, const bf16* __restrict__ Kw,
    const bf16* __restrict__ Vt, float* __restrict__ out, bf16* Pl) {
  constexpr int NF = 4 * (QT + 1);  // live 16-col score fragments (causal)
  constexpr int KS = 2 * (QT + 1);  // 32-wide K-steps for PV
  const int tid = threadIdx.x;
  const int w = tid >> 6, l = tid & 63;
  const int lr = l & 15, lg = l >> 4;
  const int t0 = QT * 64 + w * 16;  // this wave's 16 q rows

  // Q A-fragments (rows t0+lr, k-contiguous)
  const bf16* qp = Qw + ((size_t)b * 320 + t0 + lr) * 64 + lg * 8;
  const bf16x8 aq0 = *(const bf16x8*)qp;
  const bf16x8 aq1 = *(const bf16x8*)(qp + 32);

  f32x4 acc[NF];
#pragma unroll
  for (int nf = 0; nf < NF; ++nf) acc[nf] = (f32x4)0.0f;

  // S = Q K^T  (A=Q[t][h], B=K[s][h])
  const bf16* kb = Kw + ((size_t)b * 320 + lr) * 64 + lg * 8;
#pragma unroll
  for (int nf = 0; nf < NF; ++nf) {
    const bf16x8 b0 = *(const bf16x8*)(kb + nf * 1024);
    const bf16x8 b1 = *(const bf16x8*)(kb + nf * 1024 + 32);
    acc[nf] = MFMA16(aq0, b0, acc[nf]);
    acc[nf] = MFMA16(aq1, b1, acc[nf]);
  }

  // scale 1/sqrt(C)=1/32, causal mask, softmax (full row in registers)
  const int rowb = t0 + lg * 4;
  float rs[4];
#pragma unroll
  for (int r = 0; r < 4; ++r) {
    const int tg = rowb + r;
    float mx = -1e30f;
#pragma unroll
    for (int nf = 0; nf < NF; ++nf) {
      const int sg = nf * 16 + lr;
      float v = acc[nf][r] * 0.03125f;
      v = (sg > tg) ? -1e30f : v;
      acc[nf][r] = v;
      mx = fmaxf(mx, v);
    }
#pragma unroll
    for (int d = 1; d < 16; d <<= 1) mx = fmaxf(mx, __shfl_xor(mx, d));
    float sum = 0.f;
#pragma unroll
    for (int nf = 0; nf < NF; ++nf) {
      const float p = __expf(acc[nf][r] - mx);
      acc[nf][r] = p;
      sum += p;
    }
#pragma unroll
    for (int d = 1; d < 16; d <<= 1) sum += __shfl_xor(sum, d);
    rs[r] = sum;
  }

  // P -> wave-private LDS (layout conversion C-frag -> A-frag); no barrier needed
  bf16* Pw = Pl + w * (16 * 328);
#pragma unroll
  for (int nf = 0; nf < NF; ++nf)
#pragma unroll
    for (int r = 0; r < 4; ++r)
      Pw[(lg * 4 + r) * 328 + nf * 16 + lr] = (bf16)acc[nf][r];

  // O = P V   (A=P[t][s], B=Vt[h][s] read k-contiguous)
  f32x4 ao[4];
#pragma unroll
  for (int hf = 0; hf < 4; ++hf) ao[hf] = (f32x4)0.0f;
  const bf16* vb = Vt + ((size_t)b * 64 + lr) * 320 + lg * 8;
#pragma unroll
  for (int ks = 0; ks < KS; ++ks) {
    const bf16x8 ap = *(const bf16x8*)(Pw + lr * 328 + ks * 32 + lg * 8);
#pragma unroll
    for (int hf = 0; hf < 4; ++hf) {
      const bf16x8 bv = *(const bf16x8*)(vb + hf * 16 * 320 + ks * 32);
      ao[hf] = MFMA16(ap, bv, ao[hf]);
    }
  }
#pragma unroll
  for (int hf = 0; hf < 4; ++hf)
#pragma unroll
    for (int r = 0; r < 4; ++r)
      out[((size_t)b * 320 + rowb + r) * 64 + hf * 16 + lr] = ao[hf][r] / rs[r];
}

__global__ __launch_bounds__(256) void attn_kernel(
    const bf16* __restrict__ Qw, const bf16* __restrict__ Kw,
    const bf16* __restrict__ Vt, float* __restrict__ out) {
  __shared__ bf16 Pl[4 * 16 * 328];  // 41984 B -> 3 blocks/CU
  const int qt = blockIdx.x;   // 0..4
  const int b = blockIdx.y;    // 0..255
  switch (qt) {
    case 0: attn_impl<0>(b, Qw, Kw, Vt, out, Pl); break;
    case 1: attn_impl<1>(b, Qw, Kw, Vt, out, Pl); break;
    case 2: attn_impl<2>(b, Qw, Kw, Vt, out, Pl); break;
    case 3: attn_impl<3>(b, Qw, Kw, Vt, out, Pl); break;
    default: attn_impl<4>(b, Qw, Kw, Vt, out, Pl); break;
  }
}

extern "C" void kernel_launch(void* const* d_in, const int* in_sizes, int n_in,
                              void* d_out, int out_size, void* d_ws, size_t ws_size,
                              hipStream_t stream) {
  const float* x  = (const float*)d_in[0];
  const float* Wk = (const float*)d_in[1];
  const float* Wq = (const float*)d_in[2];
  const float* Wv = (const float*)d_in[3];
  float* out = (float*)d_out;

  bf16* Wt = (bf16*)d_ws;
  bf16* Qw = Wt + 3 * 64 * 1024;
  bf16* Kw = Qw + (size_t)81920 * 64;
  bf16* Vt = Kw + (size_t)81920 * 64;

  hipLaunchKernelGGL(wtrans_kernel, dim3(48), dim3(256), 0, stream, Wk, Wq, Wv, Wt);
  hipLaunchKernelGGL(qkv_kernel, dim3(1280), dim3(256), 0, stream, x, Wt, Qw, Kw, Vt);
  hipLaunchKernelGGL(attn_kernel, dim3(5, 256), dim3(256), 0, stream, Qw, Kw, Vt, out);
}

// Round 2
// 148.664 us; speedup vs baseline: 1.1357x; 1.1357x over previous
//
#include <hip/hip_runtime.h>

typedef __bf16 bf16;
typedef __bf16 bf16x4 __attribute__((ext_vector_type(4)));
typedef __bf16 bf16x8 __attribute__((ext_vector_type(8)));
typedef float f32x4 __attribute__((ext_vector_type(4)));

#define MFMA16(a, b, c) __builtin_amdgcn_mfma_f32_16x16x32_bf16((a), (b), (c), 0, 0, 0)

// B=256, T=320, C=1024, H=64;  M = B*T = 81920
// ws (bf16): Wt [3][64][1024] | Qw [81920][64] | Kw [81920][64] | Vt [256][64][320]

// ---------------- Kernel 0: W -> Wt (bf16, [mat][h][k]) ----------------
__global__ __launch_bounds__(256) void wtrans_kernel(
    const float* __restrict__ Wk, const float* __restrict__ Wq,
    const float* __restrict__ Wv, bf16* __restrict__ Wt) {
  __shared__ bf16 tile[64][65];
  const int mat = blockIdx.x >> 4;
  const int kt = (blockIdx.x & 15) << 6;
  const float* __restrict__ W = (mat == 0) ? Wk : ((mat == 1) ? Wq : Wv);
  const int tid = threadIdx.x;
#pragma unroll
  for (int j = 0; j < 16; ++j) {
    const int i = tid + 256 * j;
    const int k = i >> 6, h = i & 63;
    tile[h][k] = (bf16)W[(kt + k) * 64 + h];
  }
  __syncthreads();
#pragma unroll
  for (int j = 0; j < 16; ++j) {
    const int i = tid + 256 * j;
    const int h = i >> 6, k = i & 63;
    Wt[mat * 65536 + h * 1024 + kt + k] = tile[h][k];
  }
}

// ---------------- Kernel 1: fused QKV projection ----------------
// 1280 blocks x 256 thr (4 waves). Block: 64 rows x 192 cols. Wave: 64x48.
// Double-buffered LDS, ONE raw barrier per k-step, vmcnt never drained in loop.
__global__ __launch_bounds__(256) void qkv_kernel(
    const float* __restrict__ x, const bf16* __restrict__ Wt,
    bf16* __restrict__ Qw, bf16* __restrict__ Kw, bf16* __restrict__ Vt) {
  __shared__ bf16 xs[2][64][72];  // +8 pad: 2-way banks on b128 reads (free)
  const int tid = threadIdx.x;
  const int w = tid >> 6, l = tid & 63;
  const int lr = l & 15, lg = l >> 4;
  const int m0 = blockIdx.x * 64;

  f32x4 acc[4][3];
#pragma unroll
  for (int mf = 0; mf < 4; ++mf)
#pragma unroll
    for (int nf = 0; nf < 3; ++nf) acc[mf][nf] = (f32x4)0.0f;

  float4 g[4];
  bf16x8 wf[3][2], wn[3][2];

  auto loadx = [&](int kt) {
#pragma unroll
    for (int j = 0; j < 4; ++j) {
      const int u = tid + 256 * j;
      g[j] = *(const float4*)(x + (size_t)(m0 + (u >> 4)) * 1024 + kt + (u & 15) * 4);
    }
  };
  auto writex = [&](int buf) {
#pragma unroll
    for (int j = 0; j < 4; ++j) {
      const int u = tid + 256 * j;
      bf16x4 h4;
      h4[0] = (bf16)g[j].x; h4[1] = (bf16)g[j].y;
      h4[2] = (bf16)g[j].z; h4[3] = (bf16)g[j].w;
      *(bf16x4*)(&xs[buf][u >> 4][(u & 15) * 4]) = h4;
    }
  };
  auto loadw = [&](int kt, bf16x8 wfr[3][2]) {
#pragma unroll
    for (int nf = 0; nf < 3; ++nf) {
      const int colg = w * 48 + nf * 16 + lr;  // frag never straddles a matrix
      const bf16* p = Wt + (colg >> 6) * 65536 + (colg & 63) * 1024 + kt + lg * 8;
      wfr[nf][0] = *(const bf16x8*)p;
      wfr[nf][1] = *(const bf16x8*)(p + 32);
    }
  };

  loadx(0);
  loadw(0, wf);
#pragma unroll
  for (int t = 0; t < 16; ++t) {
    writex(t & 1);                     // vmcnt wait for g is counted, not full drain
    if (t < 15) loadx((t + 1) * 64);   // async: stays in flight across the barrier
    asm volatile("s_waitcnt lgkmcnt(0)" ::: "memory");  // ds_writes visible
    __builtin_amdgcn_sched_barrier(0);
    __builtin_amdgcn_s_barrier();      // raw barrier: does NOT drain vmcnt
    __builtin_amdgcn_sched_barrier(0);
    if (t < 15) loadw((t + 1) * 64, wn);  // prefetch next W frags (L2-hit)
#pragma unroll
    for (int mf = 0; mf < 4; ++mf) {
      const bf16x8 a0 = *(const bf16x8*)(&xs[t & 1][mf * 16 + lr][lg * 8]);
      const bf16x8 a1 = *(const bf16x8*)(&xs[t & 1][mf * 16 + lr][32 + lg * 8]);
#pragma unroll
      for (int nf = 0; nf < 3; ++nf) {
        acc[mf][nf] = MFMA16(a0, wf[nf][0], acc[mf][nf]);
        acc[mf][nf] = MFMA16(a1, wf[nf][1], acc[mf][nf]);
      }
    }
    if (t < 15) {
#pragma unroll
      for (int nf = 0; nf < 3; ++nf) {
        wf[nf][0] = wn[nf][0];
        wf[nf][1] = wn[nf][1];
      }
    }
    // no second barrier: next iter writes the OTHER buffer
  }

  // epilogue: C[i=A-row][j=B-row]; i=(lane>>4)*4+r, j=lane&15
#pragma unroll
  for (int mf = 0; mf < 4; ++mf) {
#pragma unroll
    for (int nf = 0; nf < 3; ++nf) {
      const int colg = w * 48 + nf * 16 + lr;
      const int mat = colg >> 6, h = colg & 63;
      const int mb = m0 + mf * 16 + lg * 4;  // 64 | 320: block within one batch
      if (mat == 2) {  // V transposed [b][h][t]
        const int b = mb / 320, t = mb % 320;
        bf16x4 o;
#pragma unroll
        for (int r = 0; r < 4; ++r) o[r] = (bf16)acc[mf][nf][r];
        *(bf16x4*)(Vt + ((size_t)b * 64 + h) * 320 + t) = o;
      } else {
        bf16* __restrict__ dst = (mat == 0) ? Kw : Qw;
#pragma unroll
        for (int r = 0; r < 4; ++r) dst[(size_t)(mb + r) * 64 + h] = (bf16)acc[mf][nf][r];
      }
    }
  }
}

// ---------------- Kernel 2: causal attention, swapped QK^T ----------------
// S^T = mfma(A=K, B=Q): lane holds q-row t=lane&15, s = nf*16 + (lane>>4)*4 + r.
// Softmax reduce = in-reg + 2 shuffles; P written normalized as b64.
template <int QT>
__device__ __forceinline__ void attn_impl(
    int b, const bf16* __restrict__ Qw, const bf16* __restrict__ Kw,
    const bf16* __restrict__ Vt, float* __restrict__ out, bf16* Pl) {
  constexpr int NF = 4 * (QT + 1);  // live 16-wide s fragments (causal)
  constexpr int KS = 2 * (QT + 1);  // 32-wide k-steps for PV
  constexpr int PSTR = 332;         // bank stride 6 -> 16 distinct banks
  const int tid = threadIdx.x;
  const int w = tid >> 6, l = tid & 63;
  const int lr = l & 15, lg = l >> 4;
  const int t0 = QT * 64 + w * 16;

  // Q as B-fragments (col = q row t0+lr)
  const bf16* qp = Qw + ((size_t)b * 320 + t0 + lr) * 64 + lg * 8;
  const bf16x8 bq0 = *(const bf16x8*)qp;
  const bf16x8 bq1 = *(const bf16x8*)(qp + 32);

  f32x4 acc[NF];
#pragma unroll
  for (int nf = 0; nf < NF; ++nf) acc[nf] = (f32x4)0.0f;

  // S^T: A = K rows (s), B = Q rows (t)
  const bf16* kb = Kw + ((size_t)b * 320 + lr) * 64 + lg * 8;
#pragma unroll
  for (int nf = 0; nf < NF; ++nf) {
    const bf16x8 a0 = *(const bf16x8*)(kb + nf * 1024);
    const bf16x8 a1 = *(const bf16x8*)(kb + nf * 1024 + 32);
    acc[nf] = MFMA16(a0, bq0, acc[nf]);
    acc[nf] = MFMA16(a1, bq1, acc[nf]);
  }

  // scale 1/32, causal mask, softmax over s (lane-local + 2 shuffles)
  const int tg = t0 + lr;
  float mx = -1e30f;
#pragma unroll
  for (int nf = 0; nf < NF; ++nf)
#pragma unroll
    for (int r = 0; r < 4; ++r) {
      const int sg = nf * 16 + lg * 4 + r;
      float v = acc[nf][r] * 0.03125f;
      v = (sg > tg) ? -1e30f : v;
      acc[nf][r] = v;
      mx = fmaxf(mx, v);
    }
  mx = fmaxf(mx, __shfl_xor(mx, 16));
  mx = fmaxf(mx, __shfl_xor(mx, 32));
  float sum = 0.f;
#pragma unroll
  for (int nf = 0; nf < NF; ++nf)
#pragma unroll
    for (int r = 0; r < 4; ++r) {
      const float p = __expf(acc[nf][r] - mx);
      acc[nf][r] = p;
      sum += p;
    }
  sum += __shfl_xor(sum, 16);
  sum += __shfl_xor(sum, 32);
  const float rinv = 1.0f / sum;

  // normalized P -> wave-private LDS, b64 packed (r contiguous in s)
  bf16* Pw = Pl + w * (16 * PSTR);
#pragma unroll
  for (int nf = 0; nf < NF; ++nf) {
    bf16x4 o;
#pragma unroll
    for (int r = 0; r < 4; ++r) o[r] = (bf16)(acc[nf][r] * rinv);
    *(bf16x4*)(Pw + lr * PSTR + nf * 16 + lg * 4) = o;
  }

  // O = P V  (A = P rows t, B = Vt rows h, k = s)
  f32x4 ao[4];
#pragma unroll
  for (int hf = 0; hf < 4; ++hf) ao[hf] = (f32x4)0.0f;
  const bf16* vb = Vt + ((size_t)b * 64 + lr) * 320 + lg * 8;
#pragma unroll
  for (int ks = 0; ks < KS; ++ks) {
    const bf16x8 ap = *(const bf16x8*)(Pw + lr * PSTR + ks * 32 + lg * 8);
#pragma unroll
    for (int hf = 0; hf < 4; ++hf) {
      const bf16x8 bv = *(const bf16x8*)(vb + hf * 16 * 320 + ks * 32);
      ao[hf] = MFMA16(ap, bv, ao[hf]);
    }
  }
  const int rowb = t0 + lg * 4;
#pragma unroll
  for (int hf = 0; hf < 4; ++hf)
#pragma unroll
    for (int r = 0; r < 4; ++r)
      out[((size_t)b * 320 + rowb + r) * 64 + hf * 16 + lr] = ao[hf][r];
}

__global__ __launch_bounds__(256) void attn_kernel(
    const bf16* __restrict__ Qw, const bf16* __restrict__ Kw,
    const bf16* __restrict__ Vt, float* __restrict__ out) {
  __shared__ bf16 Pl[4 * 16 * 332];  // 42.5 KB -> 3 blocks/CU
  const int b = blockIdx.x;   // 0..255  (id % 8 == b % 8: all qt of b on one XCD)
  const int qt = blockIdx.y;  // 0..4
  switch (qt) {
    case 0: attn_impl<0>(b, Qw, Kw, Vt, out, Pl); break;
    case 1: attn_impl<1>(b, Qw, Kw, Vt, out, Pl); break;
    case 2: attn_impl<2>(b, Qw, Kw, Vt, out, Pl); break;
    case 3: attn_impl<3>(b, Qw, Kw, Vt, out, Pl); break;
    default: attn_impl<4>(b, Qw, Kw, Vt, out, Pl); break;
  }
}

extern "C" void kernel_launch(void* const* d_in, const int* in_sizes, int n_in,
                              void* d_out, int out_size, void* d_ws, size_t ws_size,
                              hipStream_t stream) {
  const float* x  = (const float*)d_in[0];
  const float* Wk = (const float*)d_in[1];
  const float* Wq = (const float*)d_in[2];
  const float* Wv = (const float*)d_in[3];
  float* out = (float*)d_out;

  bf16* Wt = (bf16*)d_ws;
  bf16* Qw = Wt + 3 * 64 * 1024;
  bf16* Kw = Qw + (size_t)81920 * 64;
  bf16* Vt = Kw + (size_t)81920 * 64;

  hipLaunchKernelGGL(wtrans_kernel, dim3(48), dim3(256), 0, stream, Wk, Wq, Wv, Wt);
  hipLaunchKernelGGL(qkv_kernel, dim3(1280), dim3(256), 0, stream, x, Wt, Qw, Kw, Vt);
  hipLaunchKernelGGL(attn_kernel, dim3(256, 5), dim3(256), 0, stream, Qw, Kw, Vt, out);
}